// Round 13
// baseline (143.074 us; speedup 1.0000x reference)
//
#include <hip/hip_runtime.h>

typedef __bf16 bf16;
typedef __bf16 bf16x8 __attribute__((ext_vector_type(8)));
typedef __bf16 bf16x4 __attribute__((ext_vector_type(4)));
typedef float  f32x4  __attribute__((ext_vector_type(4)));
typedef float  f32x16 __attribute__((ext_vector_type(16)));
typedef unsigned int u32x4 __attribute__((ext_vector_type(4)));

#define MFMA16(a, b, c) __builtin_amdgcn_mfma_f32_16x16x32_bf16((a), (b), (c), 0, 0, 0)
#define MFMA32(a, b, c) __builtin_amdgcn_mfma_f32_32x32x16_bf16((a), (b), (c), 0, 0, 0)

// raw v_exp_f32: skips LLVM's denormal-range fixup (~6 insts -> 1)
__device__ __forceinline__ float fexp2(float x) {
  return __builtin_amdgcn_exp2f(x);
}

// packed f32x2 -> bf16x2 in one HW op (RNE)
__device__ __forceinline__ unsigned cvt_pk_bf16(float lo, float hi) {
  unsigned r;
  asm("v_cvt_pk_bf16_f32 %0, %1, %2" : "=v"(r) : "v"(lo), "v"(hi));
  return r;
}

// async global->LDS, 16B per lane, LDS dst = wave-uniform base + lane*16
__device__ __forceinline__ void gload_lds16(const bf16* g, bf16* l) {
  __builtin_amdgcn_global_load_lds(
      (const __attribute__((address_space(1))) void*)g,
      (__attribute__((address_space(3))) void*)l, 16, 0, 0);
}

// ---------------- prep kernels ----------------

__global__ __launch_bounds__(256) void cast_bf16_kernel(
    const float* __restrict__ in, bf16* __restrict__ out, int n4) {
  int i = blockIdx.x * 256 + threadIdx.x;
  if (i < n4) {
    float4 v = reinterpret_cast<const float4*>(in)[i];
    bf16x4 o;
    o[0] = (bf16)v.x; o[1] = (bf16)v.y; o[2] = (bf16)v.z; o[3] = (bf16)v.w;
    reinterpret_cast<bf16x4*>(out)[i] = o;
  }
}

__global__ __launch_bounds__(256) void transpose_cast_kernel(
    const float* __restrict__ W, bf16* __restrict__ Wt, int K, int N) {
  __shared__ bf16 tile[64 * 66];
  const int k0 = blockIdx.y * 64, n0 = blockIdx.x * 64;
  const int c = threadIdx.x & 63, rb = threadIdx.x >> 6;
#pragma unroll
  for (int p = 0; p < 16; ++p) {
    int r = p * 4 + rb;
    tile[c * 66 + r] = (bf16)W[(long)(k0 + r) * N + n0 + c];
  }
  __syncthreads();
#pragma unroll
  for (int p = 0; p < 16; ++p) {
    int r = p * 4 + rb;
    Wt[(long)(n0 + r) * K + k0 + c] = tile[r * 66 + c];
  }
}

// ---------------- QKV GEMM: 256x256 tile, 8 waves, phase-split pipeline ------
// C(4096,3072) = xb(4096,1024) @ wqkvT(3072,1024)^T. BK=64, 16 K-tiles.
// 512 thr = 8 waves (2M x 4N), per-wave 128x64 out = 8x4 16x16 frags.
// LDS 128KB double-buffered, XOR-swizzled (attn-proven involution).
// Counted vmcnt(2): tile t+1's first half-tile stays in flight across the
// tile-top wait (T4). Stage issue spread across the 4 MFMA phases (T3-ish),
// barriers around each MFMA cluster (role split) + setprio (T5).
__global__ __launch_bounds__(512, 2) void gemm_qkv_256(
    const bf16* __restrict__ A, const bf16* __restrict__ Bt,
    const float* __restrict__ bias, bf16* __restrict__ oQ,
    bf16* __restrict__ oK, bf16* __restrict__ oVT) {
  __shared__ bf16 As[2][256 * 64];  // 64 KB
  __shared__ bf16 Bs[2][256 * 64];  // 64 KB
  const int tid = threadIdx.x, lane = tid & 63, w = tid >> 6;
  const int wm = w >> 2, wn = w & 3;
  const int bid = blockIdx.x;
  const int swz = (bid & 7) * 24 + (bid >> 3);  // 192 % 8 == 0: bijective
  const int brow = (swz & 15) * 256, bcol = (swz >> 4) * 256;
  const int c15 = lane & 15, g = lane >> 4;
  const int srow = lane >> 3;                 // 0..7 within 8-row chunk
  const int xoff = ((lane & 7) ^ srow) << 3;  // pre-swizzled source group

  // stage one 128-row half-tile (A or B) of K-tile t into buf (2 loads/thread)
  auto stage_half = [&](int buf, int t, int h, bool isB) {
    const bf16* src = isB ? Bt : A;
    const int rb = isB ? bcol : brow;
    bf16* dst = isB ? &Bs[buf][0] : &As[buf][0];
#pragma unroll
    for (int i = 0; i < 2; ++i) {
      const int c = w * 2 + i;  // chunk 0..15 (8 rows each)
      gload_lds16(src + (long)(rb + h * 128 + c * 8 + srow) * 1024 + t * 64 + xoff,
                  dst + (h * 128 + c * 8) * 64);
    }
  };

  f32x4 acc[8][4];
#pragma unroll
  for (int mi = 0; mi < 8; ++mi)
#pragma unroll
    for (int n = 0; n < 4; ++n) acc[mi][n] = f32x4{0.f, 0.f, 0.f, 0.f};

  // prologue: stage tile 0 fully (order A0,B0,A1,B1)
  stage_half(0, 0, 0, false); stage_half(0, 0, 0, true);
  stage_half(0, 0, 1, false); stage_half(0, 0, 1, true);

  bf16x8 bfr[4];
  for (int t = 0; t < 16; ++t) {
    const int cur = t & 1;
    __builtin_amdgcn_s_barrier();  // prev tile's LDS reads done -> safe to stage
    if (t < 15) {
      stage_half(cur ^ 1, t + 1, 0, false);  // A0 of t+1
      asm volatile("s_waitcnt vmcnt(2)" ::: "memory");  // tile t staged; 2 in flight
    } else {
      asm volatile("s_waitcnt vmcnt(0)" ::: "memory");
    }
    __builtin_amdgcn_s_barrier();  // tile t visible to all waves

#pragma unroll
    for (int p = 0; p < 4; ++p) {
      const int mh = p & 1, kh = p >> 1;  // (0,0),(1,0),(0,1),(1,1)
      // ds_reads for this phase (B reloaded when kh changes: p==0, p==2)
      if (p == 0 || p == 2) {
#pragma unroll
        for (int n = 0; n < 4; ++n) {
          const int rowB = wn * 64 + n * 16 + c15;
          bfr[n] = *(const bf16x8*)&Bs[cur][rowB * 64 +
                                            (((kh * 4 + g) ^ (rowB & 7)) << 3)];
        }
      }
      bf16x8 afr[4];
#pragma unroll
      for (int m = 0; m < 4; ++m) {
        const int rowA = wm * 128 + mh * 64 + m * 16 + c15;
        afr[m] = *(const bf16x8*)&As[cur][rowA * 64 +
                                          (((kh * 4 + g) ^ (rowA & 7)) << 3)];
      }
      // stage issue interleaved with compute phases
      if (t < 15) {
        if (p == 1) stage_half(cur ^ 1, t + 1, 0, true);        // B0
        else if (p == 2) stage_half(cur ^ 1, t + 1, 1, false);  // A1
        else if (p == 3) stage_half(cur ^ 1, t + 1, 1, true);   // B1
      }
      __builtin_amdgcn_s_barrier();  // phase alignment (role split)
      __builtin_amdgcn_s_setprio(1);
#pragma unroll
      for (int m = 0; m < 4; ++m)
#pragma unroll
        for (int n = 0; n < 4; ++n)
          acc[mh * 4 + m][n] = MFMA16(afr[m], bfr[n], acc[mh * 4 + m][n]);
      __builtin_amdgcn_s_setprio(0);
      if (p < 3) __builtin_amdgcn_s_barrier();  // end-of-phase (tile-top covers p3)
    }
  }

  // epilogue: bias + Q-scale, scatter Q/K (b,h,t,d), V -> (b,h,d,t)
#pragma unroll
  for (int n = 0; n < 4; ++n) {
    const int col = bcol + wn * 64 + n * 16 + c15;
    const float bv = bias[col];
    const int which = col >> 10, wi = col & 1023, h = wi >> 6, d = wi & 63;
    const float sc = (which == 0) ? 0.18033688011112042f : 1.0f;  // 0.125*log2(e)
#pragma unroll
    for (int mi = 0; mi < 8; ++mi) {
      const int row0 = brow + wm * 128 + mi * 16 + g * 4;
      const int bb = row0 >> 11, t0 = row0 & 2047;
      const long hb = bb * 16 + h;
      if (which == 2) {
        bf16x4 pv;
#pragma unroll
        for (int r = 0; r < 4; ++r) pv[r] = (bf16)(acc[mi][n][r] + bv);
        *(bf16x4*)&oVT[(hb * 64 + d) * 2048 + t0] = pv;  // (b,h,d,t)
      } else {
        bf16* dst = ((which == 0) ? oQ : oK) + (hb * 2048 + t0) * 64 + d;
#pragma unroll
        for (int r = 0; r < 4; ++r)
          dst[(long)r * 64] = (bf16)((acc[mi][n][r] + bv) * sc);
      }
    }
  }
}

// ---------------- out-proj GEMM: C(M,N) = A(M,K) @ Bt(N,K)^T, m97 128² -------
__global__ __launch_bounds__(256, 2) void gemm_out(
    const bf16* __restrict__ A, const bf16* __restrict__ Bt,
    const float* __restrict__ bias, float* __restrict__ oC, int K) {
  __shared__ bf16 As[128 * 64];
  __shared__ bf16 Bs[128 * 64];
  const int tid = threadIdx.x, lane = tid & 63, wid = tid >> 6;
  const int wr = wid >> 1, wc = wid & 1;
  const int brow = blockIdx.x * 128, bcol = blockIdx.y * 128;
  const int srow = lane >> 3, scol8 = (lane & 7) * 8;
  const int c15 = lane & 15, g = lane >> 4;

  f32x4 acc[4][4];
#pragma unroll
  for (int m = 0; m < 4; ++m)
#pragma unroll
    for (int n = 0; n < 4; ++n) acc[m][n] = f32x4{0.f, 0.f, 0.f, 0.f};

  const bf16* Ab = A + (long)brow * K + scol8;
  const bf16* Bb = Bt + (long)bcol * K + scol8;

  for (int k0 = 0; k0 < K; k0 += 64) {
#pragma unroll
    for (int i = 0; i < 4; ++i) {
      int c = wid * 4 + i;
      int row = c * 8 + srow;
      gload_lds16(Ab + (long)row * K + k0, &As[c * 512]);
    }
#pragma unroll
    for (int i = 0; i < 4; ++i) {
      int c = wid * 4 + i;
      int row = c * 8 + srow;
      gload_lds16(Bb + (long)row * K + k0, &Bs[c * 512]);
    }
    __syncthreads();
#pragma unroll
    for (int kk = 0; kk < 64; kk += 32) {
      bf16x8 a[4], b[4];
#pragma unroll
      for (int m = 0; m < 4; ++m)
        a[m] = *(const bf16x8*)&As[(wr * 64 + m * 16 + c15) * 64 + kk + g * 8];
#pragma unroll
      for (int n = 0; n < 4; ++n)
        b[n] = *(const bf16x8*)&Bs[(wc * 64 + n * 16 + c15) * 64 + kk + g * 8];
#pragma unroll
      for (int m = 0; m < 4; ++m)
#pragma unroll
        for (int n = 0; n < 4; ++n)
          acc[m][n] = MFMA16(a[m], b[n], acc[m][n]);
    }
    __syncthreads();
  }

#pragma unroll
  for (int n = 0; n < 4; ++n) {
    const int col = bcol + wc * 64 + n * 16 + c15;
    const float bv = bias[col];
#pragma unroll
    for (int m = 0; m < 4; ++m) {
      const long row = brow + wr * 64 + m * 16 + g * 4;
#pragma unroll
      for (int r = 0; r < 4; ++r) oC[(row + r) * 1024 + col] = acc[m][n][r] + bv;
    }
  }
}

// ---------------- flash attention: staged K/V, IN-BLOCK KV-split x2 ----------
__global__ __launch_bounds__(512, 4) void attn_kernel(
    const bf16* __restrict__ Q, const bf16* __restrict__ K,
    const bf16* __restrict__ VT, const int* __restrict__ mask,
    bf16* __restrict__ Aout) {
  __shared__ bf16 Kl[2][2][4096];   // [stream][buf][64 keys x 64 kdim], XOR-swz
  __shared__ bf16 Vl[2][2][4096];   // [stream][buf][64 d x 64 keys]
  __shared__ float sws[8][32];      // rare-path rescale broadcast
  __shared__ float mlL[2][4][2][32];// [split][q-group][{m,l}][query]
  const int tid = threadIdx.x, lane = tid & 63, w = tid >> 6;
  const int wq = w & 3, s = w >> 2;
  const int col = lane & 31, hi = lane >> 5, c7 = col & 7;
  const int bid = blockIdx.x;
  const int swz = (bid & 7) * 64 + (bid >> 3);  // XCD swizzle (512 % 8 == 0)
  const int bh = swz >> 4, qb = swz & 15;
  const int b = bh >> 4, h = bh & 15;
  const int q0 = qb * 128 + wq * 32;
  const int koff0 = s * 1024;

  const bf16* Kbase = K + (long)bh * 2048 * 64;
  const bf16* Vbase = VT + (long)bh * 64 * 2048;
  const int* mb = mask + b * 2048;

  const int srow = lane >> 3;
  const int xoff = ((lane & 7) ^ srow) << 3;

  auto stage = [&](int buf, int t) {
    const int koff = koff0 + t * 64;
#pragma unroll
    for (int i = 0; i < 2; ++i) {
      const int c = wq * 2 + i;
      gload_lds16(Kbase + (long)(koff + c * 8 + srow) * 64 + xoff,
                  &Kl[s][buf][c * 512]);
      gload_lds16(Vbase + (long)(c * 8 + srow) * 2048 + koff + xoff,
                  &Vl[s][buf][c * 512]);
    }
  };

  // Q B-frag (pre-scaled by 0.125*log2e in gemm epilogue)
  const bf16* Qp = Q + ((long)bh * 2048 + q0 + col) * 64 + hi * 8;
  bf16x8 bq[4];
#pragma unroll
  for (int dc = 0; dc < 4; ++dc) bq[dc] = *(const bf16x8*)(Qp + dc * 16);

  f32x16 o0, o1;
#pragma unroll
  for (int r = 0; r < 16; ++r) { o0[r] = 0.f; o1[r] = 0.f; }
  float mrun = -1e30f, lrun = 0.f;  // lrun = per-half partial until fold

  stage(0, 0);
  for (int t = 0; t < 16; ++t) {
    const int cur = t & 1;
    __builtin_amdgcn_s_barrier();  // prev tile's LDS reads done before overwrite
    const int mvA = mb[koff0 + t * 64 + col];
    const int mvB = mb[koff0 + t * 64 + 32 + col];
    if (t < 15) {
      stage(cur ^ 1, t + 1);
      asm volatile("s_waitcnt vmcnt(6)" ::: "memory");
    } else {
      asm volatile("s_waitcnt vmcnt(0)" ::: "memory");
    }
    __builtin_amdgcn_s_barrier();  // all waves' chunks of tile t visible

#pragma unroll
    for (int sub = 0; sub < 2; ++sub) {
      const int mv = (sub == 0) ? mvA : mvB;
      const bf16* Krow = &Kl[s][cur][(sub * 32 + col) * 64];
      bf16x8 ak0 = *(const bf16x8*)(Krow + (((0 + hi) ^ c7) << 3));
      bf16x8 ak1 = *(const bf16x8*)(Krow + (((2 + hi) ^ c7) << 3));
      bf16x8 ak2 = *(const bf16x8*)(Krow + (((4 + hi) ^ c7) << 3));
      bf16x8 ak3 = *(const bf16x8*)(Krow + (((6 + hi) ^ c7) << 3));
      f32x16 st;
#pragma unroll
      for (int r = 0; r < 16; ++r) st[r] = 0.f;
      __builtin_amdgcn_s_setprio(1);
      st = MFMA32(ak0, bq[0], st);
      st = MFMA32(ak1, bq[1], st);
      st = MFMA32(ak2, bq[2], st);
      st = MFMA32(ak3, bq[3], st);
      __builtin_amdgcn_s_setprio(0);
      unsigned km32 = (unsigned)__ballot(mv != 0);
      if (km32 != 0xffffffffu) {
        unsigned km = km32 >> (hi * 4);
#pragma unroll
        for (int r = 0; r < 16; ++r)
          if (!((km >> ((r & 3) + 8 * (r >> 2))) & 1)) st[r] = -1e30f;
      }
      float m01 = fmaxf(st[0], st[1]), m23 = fmaxf(st[2], st[3]);
      float m45 = fmaxf(st[4], st[5]), m67 = fmaxf(st[6], st[7]);
      float m89 = fmaxf(st[8], st[9]), mab = fmaxf(st[10], st[11]);
      float mcd = fmaxf(st[12], st[13]), mef = fmaxf(st[14], st[15]);
      float m0 = fmaxf(fmaxf(fmaxf(m01, m23), fmaxf(m45, m67)),
                       fmaxf(fmaxf(m89, mab), fmaxf(mcd, mef)));
      if (__any(m0 > mrun + 8.0f)) {
        float pm = fmaxf(m0, __shfl_xor(m0, 32));
        float mnew = fmaxf(mrun, pm);
        float scale = fexp2(mrun - mnew);
        mrun = mnew;
        lrun *= scale;
        if (hi == 0) sws[w][col] = scale;
        asm volatile("s_waitcnt lgkmcnt(0)" ::: "memory");
#pragma unroll
        for (int r = 0; r < 16; ++r) {
          float sc = sws[w][(r & 3) + 8 * (r >> 2) + 4 * hi];
          o0[r] *= sc; o1[r] *= sc;
        }
      }
#pragma unroll
      for (int r = 0; r < 16; ++r) st[r] = fexp2(st[r] - mrun);
      float s01 = st[0] + st[1], s23 = st[2] + st[3], s45 = st[4] + st[5];
      float s67 = st[6] + st[7], s89 = st[8] + st[9], sab = st[10] + st[11];
      float scd = st[12] + st[13], sef = st[14] + st[15];
      lrun += ((s01 + s23) + (s45 + s67)) + ((s89 + sab) + (scd + sef));
      unsigned d0 = cvt_pk_bf16(st[0], st[1]);
      unsigned d1 = cvt_pk_bf16(st[2], st[3]);
      unsigned d2 = cvt_pk_bf16(st[4], st[5]);
      unsigned d3 = cvt_pk_bf16(st[6], st[7]);
      unsigned d4 = cvt_pk_bf16(st[8], st[9]);
      unsigned d5 = cvt_pk_bf16(st[10], st[11]);
      unsigned d6 = cvt_pk_bf16(st[12], st[13]);
      unsigned d7 = cvt_pk_bf16(st[14], st[15]);
      unsigned g02 = (unsigned)__shfl_xor((int)(hi ? d0 : d2), 32);
      unsigned g13 = (unsigned)__shfl_xor((int)(hi ? d1 : d3), 32);
      unsigned g46 = (unsigned)__shfl_xor((int)(hi ? d4 : d6), 32);
      unsigned g57 = (unsigned)__shfl_xor((int)(hi ? d5 : d7), 32);
      u32x4 w0 = {hi ? g02 : d0, hi ? g13 : d1, hi ? d2 : g02, hi ? d3 : g13};
      u32x4 w1 = {hi ? g46 : d4, hi ? g57 : d5, hi ? d6 : g46, hi ? d7 : g57};
      bf16x8 pa0 = __builtin_bit_cast(bf16x8, w0);
      bf16x8 pa1 = __builtin_bit_cast(bf16x8, w1);
      const bf16* Vrow0 = &Vl[s][cur][col * 64];
      const bf16* Vrow1 = &Vl[s][cur][(col + 32) * 64];
      const int g0 = ((sub * 4 + hi) ^ c7) << 3;
      const int g1 = ((sub * 4 + 2 + hi) ^ c7) << 3;
      bf16x8 bv00 = *(const bf16x8*)(Vrow0 + g0);
      bf16x8 bv10 = *(const bf16x8*)(Vrow0 + g1);
      bf16x8 bv01 = *(const bf16x8*)(Vrow1 + g0);
      bf16x8 bv11 = *(const bf16x8*)(Vrow1 + g1);
      __builtin_amdgcn_s_setprio(1);
      o0 = MFMA32(pa0, bv00, o0);
      o0 = MFMA32(pa1, bv10, o0);
      o1 = MFMA32(pa0, bv01, o1);
      o1 = MFMA32(pa1, bv11, o1);
      __builtin_amdgcn_s_setprio(0);
    }
  }

  // ---- in-LDS merge of the 2 KV-split partials ----
  lrun += __shfl_xor(lrun, 32);  // fold per-half l partials
  if (hi == 0) { mlL[s][wq][0][col] = mrun; mlL[s][wq][1][col] = lrun; }
  __syncthreads();  // all loop LDS reads done; mlL visible

  float* Ol = (float*)Kl;  // 32 KB staging region, dead now
  if (s == 1) {
#pragma unroll
    for (int r = 0; r < 16; ++r) {
      Ol[(wq * 16 + r) * 128 + lane] = o0[r];
      Ol[(wq * 16 + r) * 128 + 64 + lane] = o1[r];
    }
  }
  __syncthreads();  // split-1 O visible

  if (s == 0) {
#pragma unroll
    for (int r = 0; r < 16; ++r) {
      const int qr = (r & 3) + 8 * (r >> 2) + 4 * hi;
      float m0v = mlL[0][wq][0][qr], l0v = mlL[0][wq][1][qr];
      float m1v = mlL[1][wq][0][qr], l1v = mlL[1][wq][1][qr];
      float ms = fmaxf(m0v, m1v);
      float w0v = fexp2(m0v - ms), w1v = fexp2(m1v - ms);
      float inv = 1.0f / (w0v * l0v + w1v * l1v);
      float v0 = (w0v * o0[r] + w1v * Ol[(wq * 16 + r) * 128 + lane]) * inv;
      float v1 = (w0v * o1[r] + w1v * Ol[(wq * 16 + r) * 128 + 64 + lane]) * inv;
      long base = ((long)b * 2048 + q0 + qr) * 1024 + h * 64 + col;
      Aout[base] = (bf16)v0;
      Aout[base + 32] = (bf16)v1;
    }
  }
}

// ---------------- launcher ----------------
extern "C" void kernel_launch(void* const* d_in, const int* in_sizes, int n_in,
                              void* d_out, int out_size, void* d_ws,
                              size_t ws_size, hipStream_t stream) {
  const float* x    = (const float*)d_in[0];
  const int*   mask = (const int*)d_in[1];
  const float* Wqkv = (const float*)d_in[2];
  const float* bqkv = (const float*)d_in[3];
  const float* Wout = (const float*)d_in[4];
  const float* bout = (const float*)d_in[5];
  float* out = (float*)d_out;

  char* ws = (char*)d_ws;
  bf16* xb    = (bf16*)(ws);                      // 8 MB; reused as Aatt
  bf16* wqkvT = (bf16*)(ws + (8u << 20));         // 6 MB
  bf16* woutT = (bf16*)(ws + (14u << 20));        // 2 MB
  bf16* Qb    = (bf16*)(ws + (16u << 20));        // 8 MB (b,h,t,d)
  bf16* Kb    = (bf16*)(ws + (24u << 20));        // 8 MB (b,h,t,d)
  bf16* VTb   = (bf16*)(ws + (32u << 20));        // 8 MB (b,h,d,t)
  bf16* Aatt  = xb;

  cast_bf16_kernel<<<4096, 256, 0, stream>>>(x, xb, (4096 * 1024) / 4);
  transpose_cast_kernel<<<dim3(48, 16), 256, 0, stream>>>(Wqkv, wqkvT, 1024, 3072);
  transpose_cast_kernel<<<dim3(16, 16), 256, 0, stream>>>(Wout, woutT, 1024, 1024);
  gemm_qkv_256<<<192, 512, 0, stream>>>(xb, wqkvT, bqkv, Qb, Kb, VTb);
  attn_kernel<<<512, 512, 0, stream>>>(Qb, Kb, VTb, mask, Aatt);
  gemm_out<<<dim3(32, 8), 256, 0, stream>>>(Aatt, woutT, bout, out, 1024);
}

// Round 14
// 124.953 us; speedup vs baseline: 1.1450x; 1.1450x over previous
//
#include <hip/hip_runtime.h>

typedef __bf16 bf16;
typedef __bf16 bf16x8 __attribute__((ext_vector_type(8)));
typedef __bf16 bf16x4 __attribute__((ext_vector_type(4)));
typedef float  f32x4  __attribute__((ext_vector_type(4)));
typedef float  f32x16 __attribute__((ext_vector_type(16)));
typedef unsigned int u32x4 __attribute__((ext_vector_type(4)));

#define MFMA16(a, b, c) __builtin_amdgcn_mfma_f32_16x16x32_bf16((a), (b), (c), 0, 0, 0)
#define MFMA32(a, b, c) __builtin_amdgcn_mfma_f32_32x32x16_bf16((a), (b), (c), 0, 0, 0)

// raw v_exp_f32: skips LLVM's denormal-range fixup (~6 insts -> 1)
__device__ __forceinline__ float fexp2(float x) {
  return __builtin_amdgcn_exp2f(x);
}

// packed f32x2 -> bf16x2 in one HW op (RNE)
__device__ __forceinline__ unsigned cvt_pk_bf16(float lo, float hi) {
  unsigned r;
  asm("v_cvt_pk_bf16_f32 %0, %1, %2" : "=v"(r) : "v"(lo), "v"(hi));
  return r;
}

// async global->LDS, 16B per lane, LDS dst = wave-uniform base + lane*16
__device__ __forceinline__ void gload_lds16(const bf16* g, bf16* l) {
  __builtin_amdgcn_global_load_lds(
      (const __attribute__((address_space(1))) void*)g,
      (__attribute__((address_space(3))) void*)l, 16, 0, 0);
}

// ---------------- fused prep: cast x -> bf16 + both W transposes -------------
// blocks [0,4096): cast; [4096,4864): W_qkv transpose; [4864,5120): W_out.
__global__ __launch_bounds__(256) void prep_kernel(
    const float* __restrict__ x, bf16* __restrict__ xb,
    const float* __restrict__ Wqkv, bf16* __restrict__ wqkvT,
    const float* __restrict__ Wout, bf16* __restrict__ woutT) {
  __shared__ bf16 tile[64 * 66];
  const int bid = blockIdx.x, tid = threadIdx.x;
  if (bid < 4096) {  // cast: 4 fp32 -> bf16 per thread
    int i = bid * 256 + tid;
    float4 v = reinterpret_cast<const float4*>(x)[i];
    bf16x4 o;
    o[0] = (bf16)v.x; o[1] = (bf16)v.y; o[2] = (bf16)v.z; o[3] = (bf16)v.w;
    reinterpret_cast<bf16x4*>(xb)[i] = o;
    return;
  }
  // transpose-cast: W (K,N) fp32 -> Wt (N,K) bf16, 64x64 tiles, stride 66
  const float* W; bf16* Wt; int K, N, bx, by;
  if (bid < 4864) {
    W = Wqkv; Wt = wqkvT; K = 1024; N = 3072;
    int r = bid - 4096; bx = r % 48; by = r / 48;
  } else {
    W = Wout; Wt = woutT; K = 1024; N = 1024;
    int r = bid - 4864; bx = r % 16; by = r / 16;
  }
  const int k0 = by * 64, n0 = bx * 64;
  const int c = tid & 63, rb = tid >> 6;
#pragma unroll
  for (int p = 0; p < 16; ++p) {
    int r = p * 4 + rb;
    tile[c * 66 + r] = (bf16)W[(long)(k0 + r) * N + n0 + c];
  }
  __syncthreads();
#pragma unroll
  for (int p = 0; p < 16; ++p) {
    int r = p * 4 + rb;
    Wt[(long)(n0 + r) * K + k0 + c] = tile[r * 66 + c];
  }
}

// ---------------- QKV GEMM: m97 128² structure (round-12 verified) -----------
__global__ __launch_bounds__(256, 2) void gemm_qkv(
    const bf16* __restrict__ A, const bf16* __restrict__ Bt,
    const float* __restrict__ bias, bf16* __restrict__ oQ,
    bf16* __restrict__ oK, bf16* __restrict__ oVT) {
  __shared__ bf16 As[128 * 64];
  __shared__ bf16 Bs[128 * 64];
  const int K = 1024;
  const int tid = threadIdx.x, lane = tid & 63, wid = tid >> 6;
  const int wr = wid >> 1, wc = wid & 1;
  const int brow = blockIdx.x * 128, bcol = blockIdx.y * 128;
  const int srow = lane >> 3, scol8 = (lane & 7) * 8;
  const int c15 = lane & 15, g = lane >> 4;

  f32x4 acc[4][4];
#pragma unroll
  for (int m = 0; m < 4; ++m)
#pragma unroll
    for (int n = 0; n < 4; ++n) acc[m][n] = f32x4{0.f, 0.f, 0.f, 0.f};

  const bf16* Ab = A + (long)brow * K + scol8;
  const bf16* Bb = Bt + (long)bcol * K + scol8;

  for (int k0 = 0; k0 < K; k0 += 64) {
#pragma unroll
    for (int i = 0; i < 4; ++i) {
      int c = wid * 4 + i;
      int row = c * 8 + srow;
      gload_lds16(Ab + (long)row * K + k0, &As[c * 512]);
    }
#pragma unroll
    for (int i = 0; i < 4; ++i) {
      int c = wid * 4 + i;
      int row = c * 8 + srow;
      gload_lds16(Bb + (long)row * K + k0, &Bs[c * 512]);
    }
    __syncthreads();
#pragma unroll
    for (int kk = 0; kk < 64; kk += 32) {
      bf16x8 a[4], b[4];
#pragma unroll
      for (int m = 0; m < 4; ++m)
        a[m] = *(const bf16x8*)&As[(wr * 64 + m * 16 + c15) * 64 + kk + g * 8];
#pragma unroll
      for (int n = 0; n < 4; ++n)
        b[n] = *(const bf16x8*)&Bs[(wc * 64 + n * 16 + c15) * 64 + kk + g * 8];
#pragma unroll
      for (int m = 0; m < 4; ++m)
#pragma unroll
        for (int n = 0; n < 4; ++n)
          acc[m][n] = MFMA16(a[m], b[n], acc[m][n]);
    }
    __syncthreads();
  }

  // epilogue: bias + Q-scale; scatter Q/K (b,h,t,d), V -> (b,h,d,t)
#pragma unroll
  for (int n = 0; n < 4; ++n) {
    const int col = bcol + wc * 64 + n * 16 + c15;
    const float bv = bias[col];
    const int which = col >> 10, wi = col & 1023, h = wi >> 6, d = wi & 63;
    const float sc = (which == 0) ? 0.18033688011112042f : 1.0f;  // 0.125*log2(e)
#pragma unroll
    for (int m = 0; m < 4; ++m) {
      const int row0 = brow + wr * 64 + m * 16 + g * 4;
      const int bb = row0 >> 11, t0 = row0 & 2047;
      const long hb = bb * 16 + h;
      if (which == 2) {
        bf16x4 pv;
#pragma unroll
        for (int r = 0; r < 4; ++r) pv[r] = (bf16)(acc[m][n][r] + bv);
        *(bf16x4*)&oVT[(hb * 64 + d) * 2048 + t0] = pv;  // (b,h,d,t)
      } else {
        bf16* dst = ((which == 0) ? oQ : oK) + (hb * 2048 + t0) * 64 + d;
#pragma unroll
        for (int r = 0; r < 4; ++r)
          dst[(long)r * 64] = (bf16)((acc[m][n][r] + bv) * sc);
      }
    }
  }
}

// ---------------- out-proj GEMM: 128x64 tile (2+ blocks/CU for N=1024) -------
// Round-14: gemm1 at 128² had grid 256 = 1 block/CU = 1 wave/SIMD (worst
// occupancy in the pipeline). 128x64 -> 512 blocks, 24KB LDS, acc[4][2].
__global__ __launch_bounds__(256, 2) void gemm_out(
    const bf16* __restrict__ A, const bf16* __restrict__ Bt,
    const float* __restrict__ bias, float* __restrict__ oC, int K) {
  __shared__ bf16 As[128 * 64];
  __shared__ bf16 Bs[64 * 64];
  const int tid = threadIdx.x, lane = tid & 63, wid = tid >> 6;
  const int wr = wid >> 1, wc = wid & 1;
  const int brow = blockIdx.x * 128, bcol = blockIdx.y * 64;
  const int srow = lane >> 3, scol8 = (lane & 7) * 8;
  const int c15 = lane & 15, g = lane >> 4;

  f32x4 acc[4][2];
#pragma unroll
  for (int m = 0; m < 4; ++m)
#pragma unroll
    for (int n = 0; n < 2; ++n) acc[m][n] = f32x4{0.f, 0.f, 0.f, 0.f};

  const bf16* Ab = A + (long)brow * K + scol8;
  const bf16* Bb = Bt + (long)bcol * K + scol8;

  for (int k0 = 0; k0 < K; k0 += 64) {
#pragma unroll
    for (int i = 0; i < 4; ++i) {
      int c = wid * 4 + i;
      int row = c * 8 + srow;
      gload_lds16(Ab + (long)row * K + k0, &As[c * 512]);
    }
#pragma unroll
    for (int i = 0; i < 2; ++i) {
      int c = wid * 2 + i;
      int row = c * 8 + srow;
      gload_lds16(Bb + (long)row * K + k0, &Bs[c * 512]);
    }
    __syncthreads();
#pragma unroll
    for (int kk = 0; kk < 64; kk += 32) {
      bf16x8 a[4], b[2];
#pragma unroll
      for (int m = 0; m < 4; ++m)
        a[m] = *(const bf16x8*)&As[(wr * 64 + m * 16 + c15) * 64 + kk + g * 8];
#pragma unroll
      for (int n = 0; n < 2; ++n)
        b[n] = *(const bf16x8*)&Bs[(wc * 32 + n * 16 + c15) * 64 + kk + g * 8];
#pragma unroll
      for (int m = 0; m < 4; ++m)
#pragma unroll
        for (int n = 0; n < 2; ++n)
          acc[m][n] = MFMA16(a[m], b[n], acc[m][n]);
    }
    __syncthreads();
  }

#pragma unroll
  for (int n = 0; n < 2; ++n) {
    const int col = bcol + wc * 32 + n * 16 + c15;
    const float bv = bias[col];
#pragma unroll
    for (int m = 0; m < 4; ++m) {
      const long row = brow + wr * 64 + m * 16 + g * 4;
#pragma unroll
      for (int r = 0; r < 4; ++r) oC[(row + r) * 1024 + col] = acc[m][n][r] + bv;
    }
  }
}

// ---------------- flash attention: staged K/V, IN-BLOCK KV-split x2 ----------
__global__ __launch_bounds__(512, 4) void attn_kernel(
    const bf16* __restrict__ Q, const bf16* __restrict__ K,
    const bf16* __restrict__ VT, const int* __restrict__ mask,
    bf16* __restrict__ Aout) {
  __shared__ bf16 Kl[2][2][4096];   // [stream][buf][64 keys x 64 kdim], XOR-swz
  __shared__ bf16 Vl[2][2][4096];   // [stream][buf][64 d x 64 keys]
  __shared__ float sws[8][32];      // rare-path rescale broadcast
  __shared__ float mlL[2][4][2][32];// [split][q-group][{m,l}][query]
  const int tid = threadIdx.x, lane = tid & 63, w = tid >> 6;
  const int wq = w & 3, s = w >> 2;
  const int col = lane & 31, hi = lane >> 5, c7 = col & 7;
  const int bid = blockIdx.x;
  const int swz = (bid & 7) * 64 + (bid >> 3);  // XCD swizzle (512 % 8 == 0)
  const int bh = swz >> 4, qb = swz & 15;
  const int b = bh >> 4, h = bh & 15;
  const int q0 = qb * 128 + wq * 32;
  const int koff0 = s * 1024;

  const bf16* Kbase = K + (long)bh * 2048 * 64;
  const bf16* Vbase = VT + (long)bh * 64 * 2048;
  const int* mb = mask + b * 2048;

  const int srow = lane >> 3;
  const int xoff = ((lane & 7) ^ srow) << 3;

  auto stage = [&](int buf, int t) {
    const int koff = koff0 + t * 64;
#pragma unroll
    for (int i = 0; i < 2; ++i) {
      const int c = wq * 2 + i;
      gload_lds16(Kbase + (long)(koff + c * 8 + srow) * 64 + xoff,
                  &Kl[s][buf][c * 512]);
      gload_lds16(Vbase + (long)(c * 8 + srow) * 2048 + koff + xoff,
                  &Vl[s][buf][c * 512]);
    }
  };

  // Q B-frag (pre-scaled by 0.125*log2e in gemm epilogue)
  const bf16* Qp = Q + ((long)bh * 2048 + q0 + col) * 64 + hi * 8;
  bf16x8 bq[4];
#pragma unroll
  for (int dc = 0; dc < 4; ++dc) bq[dc] = *(const bf16x8*)(Qp + dc * 16);

  f32x16 o0, o1;
#pragma unroll
  for (int r = 0; r < 16; ++r) { o0[r] = 0.f; o1[r] = 0.f; }
  float mrun = -1e30f, lrun = 0.f;  // lrun = per-half partial until fold

  stage(0, 0);
  for (int t = 0; t < 16; ++t) {
    const int cur = t & 1;
    __builtin_amdgcn_s_barrier();  // prev tile's LDS reads done before overwrite
    const int mvA = mb[koff0 + t * 64 + col];
    const int mvB = mb[koff0 + t * 64 + 32 + col];
    if (t < 15) {
      stage(cur ^ 1, t + 1);
      asm volatile("s_waitcnt vmcnt(6)" ::: "memory");
    } else {
      asm volatile("s_waitcnt vmcnt(0)" ::: "memory");
    }
    __builtin_amdgcn_s_barrier();  // all waves' chunks of tile t visible

#pragma unroll
    for (int sub = 0; sub < 2; ++sub) {
      const int mv = (sub == 0) ? mvA : mvB;
      const bf16* Krow = &Kl[s][cur][(sub * 32 + col) * 64];
      bf16x8 ak0 = *(const bf16x8*)(Krow + (((0 + hi) ^ c7) << 3));
      bf16x8 ak1 = *(const bf16x8*)(Krow + (((2 + hi) ^ c7) << 3));
      bf16x8 ak2 = *(const bf16x8*)(Krow + (((4 + hi) ^ c7) << 3));
      bf16x8 ak3 = *(const bf16x8*)(Krow + (((6 + hi) ^ c7) << 3));
      f32x16 st;
#pragma unroll
      for (int r = 0; r < 16; ++r) st[r] = 0.f;
      __builtin_amdgcn_s_setprio(1);
      st = MFMA32(ak0, bq[0], st);
      st = MFMA32(ak1, bq[1], st);
      st = MFMA32(ak2, bq[2], st);
      st = MFMA32(ak3, bq[3], st);
      __builtin_amdgcn_s_setprio(0);
      unsigned km32 = (unsigned)__ballot(mv != 0);
      if (km32 != 0xffffffffu) {
        unsigned km = km32 >> (hi * 4);
#pragma unroll
        for (int r = 0; r < 16; ++r)
          if (!((km >> ((r & 3) + 8 * (r >> 2))) & 1)) st[r] = -1e30f;
      }
      float m01 = fmaxf(st[0], st[1]), m23 = fmaxf(st[2], st[3]);
      float m45 = fmaxf(st[4], st[5]), m67 = fmaxf(st[6], st[7]);
      float m89 = fmaxf(st[8], st[9]), mab = fmaxf(st[10], st[11]);
      float mcd = fmaxf(st[12], st[13]), mef = fmaxf(st[14], st[15]);
      float m0 = fmaxf(fmaxf(fmaxf(m01, m23), fmaxf(m45, m67)),
                       fmaxf(fmaxf(m89, mab), fmaxf(mcd, mef)));
      if (__any(m0 > mrun + 8.0f)) {
        float pm = fmaxf(m0, __shfl_xor(m0, 32));
        float mnew = fmaxf(mrun, pm);
        float scale = fexp2(mrun - mnew);
        mrun = mnew;
        lrun *= scale;
        if (hi == 0) sws[w][col] = scale;
        asm volatile("s_waitcnt lgkmcnt(0)" ::: "memory");
#pragma unroll
        for (int r = 0; r < 16; ++r) {
          float sc = sws[w][(r & 3) + 8 * (r >> 2) + 4 * hi];
          o0[r] *= sc; o1[r] *= sc;
        }
      }
#pragma unroll
      for (int r = 0; r < 16; ++r) st[r] = fexp2(st[r] - mrun);
      float s01 = st[0] + st[1], s23 = st[2] + st[3], s45 = st[4] + st[5];
      float s67 = st[6] + st[7], s89 = st[8] + st[9], sab = st[10] + st[11];
      float scd = st[12] + st[13], sef = st[14] + st[15];
      lrun += ((s01 + s23) + (s45 + s67)) + ((s89 + sab) + (scd + sef));
      unsigned d0 = cvt_pk_bf16(st[0], st[1]);
      unsigned d1 = cvt_pk_bf16(st[2], st[3]);
      unsigned d2 = cvt_pk_bf16(st[4], st[5]);
      unsigned d3 = cvt_pk_bf16(st[6], st[7]);
      unsigned d4 = cvt_pk_bf16(st[8], st[9]);
      unsigned d5 = cvt_pk_bf16(st[10], st[11]);
      unsigned d6 = cvt_pk_bf16(st[12], st[13]);
      unsigned d7 = cvt_pk_bf16(st[14], st[15]);
      unsigned g02 = (unsigned)__shfl_xor((int)(hi ? d0 : d2), 32);
      unsigned g13 = (unsigned)__shfl_xor((int)(hi ? d1 : d3), 32);
      unsigned g46 = (unsigned)__shfl_xor((int)(hi ? d4 : d6), 32);
      unsigned g57 = (unsigned)__shfl_xor((int)(hi ? d5 : d7), 32);
      u32x4 w0 = {hi ? g02 : d0, hi ? g13 : d1, hi ? d2 : g02, hi ? d3 : g13};
      u32x4 w1 = {hi ? g46 : d4, hi ? g57 : d5, hi ? d6 : g46, hi ? d7 : g57};
      bf16x8 pa0 = __builtin_bit_cast(bf16x8, w0);
      bf16x8 pa1 = __builtin_bit_cast(bf16x8, w1);
      const bf16* Vrow0 = &Vl[s][cur][col * 64];
      const bf16* Vrow1 = &Vl[s][cur][(col + 32) * 64];
      const int g0 = ((sub * 4 + hi) ^ c7) << 3;
      const int g1 = ((sub * 4 + 2 + hi) ^ c7) << 3;
      bf16x8 bv00 = *(const bf16x8*)(Vrow0 + g0);
      bf16x8 bv10 = *(const bf16x8*)(Vrow0 + g1);
      bf16x8 bv01 = *(const bf16x8*)(Vrow1 + g0);
      bf16x8 bv11 = *(const bf16x8*)(Vrow1 + g1);
      __builtin_amdgcn_s_setprio(1);
      o0 = MFMA32(pa0, bv00, o0);
      o0 = MFMA32(pa1, bv10, o0);
      o1 = MFMA32(pa0, bv01, o1);
      o1 = MFMA32(pa1, bv11, o1);
      __builtin_amdgcn_s_setprio(0);
    }
  }

  // ---- in-LDS merge of the 2 KV-split partials ----
  lrun += __shfl_xor(lrun, 32);  // fold per-half l partials
  if (hi == 0) { mlL[s][wq][0][col] = mrun; mlL[s][wq][1][col] = lrun; }
  __syncthreads();  // all loop LDS reads done; mlL visible

  float* Ol = (float*)Kl;  // 32 KB staging region, dead now
  if (s == 1) {
#pragma unroll
    for (int r = 0; r < 16; ++r) {
      Ol[(wq * 16 + r) * 128 + lane] = o0[r];
      Ol[(wq * 16 + r) * 128 + 64 + lane] = o1[r];
    }
  }
  __syncthreads();  // split-1 O visible

  if (s == 0) {
#pragma unroll
    for (int r = 0; r < 16; ++r) {
      const int qr = (r & 3) + 8 * (r >> 2) + 4 * hi;
      float m0v = mlL[0][wq][0][qr], l0v = mlL[0][wq][1][qr];
      float m1v = mlL[1][wq][0][qr], l1v = mlL[1][wq][1][qr];
      float ms = fmaxf(m0v, m1v);
      float w0v = fexp2(m0v - ms), w1v = fexp2(m1v - ms);
      float inv = 1.0f / (w0v * l0v + w1v * l1v);
      float v0 = (w0v * o0[r] + w1v * Ol[(wq * 16 + r) * 128 + lane]) * inv;
      float v1 = (w0v * o1[r] + w1v * Ol[(wq * 16 + r) * 128 + 64 + lane]) * inv;
      long base = ((long)b * 2048 + q0 + qr) * 1024 + h * 64 + col;
      Aout[base] = (bf16)v0;
      Aout[base + 32] = (bf16)v1;
    }
  }
}

// ---------------- launcher ----------------
extern "C" void kernel_launch(void* const* d_in, const int* in_sizes, int n_in,
                              void* d_out, int out_size, void* d_ws,
                              size_t ws_size, hipStream_t stream) {
  const float* x    = (const float*)d_in[0];
  const int*   mask = (const int*)d_in[1];
  const float* Wqkv = (const float*)d_in[2];
  const float* bqkv = (const float*)d_in[3];
  const float* Wout = (const float*)d_in[4];
  const float* bout = (const float*)d_in[5];
  float* out = (float*)d_out;

  char* ws = (char*)d_ws;
  bf16* xb    = (bf16*)(ws);                      // 8 MB; reused as Aatt
  bf16* wqkvT = (bf16*)(ws + (8u << 20));         // 6 MB
  bf16* woutT = (bf16*)(ws + (14u << 20));        // 2 MB
  bf16* Qb    = (bf16*)(ws + (16u << 20));        // 8 MB (b,h,t,d)
  bf16* Kb    = (bf16*)(ws + (24u << 20));        // 8 MB (b,h,t,d)
  bf16* VTb   = (bf16*)(ws + (32u << 20));        // 8 MB (b,h,d,t)
  bf16* Aatt  = xb;

  prep_kernel<<<5120, 256, 0, stream>>>(x, xb, Wqkv, wqkvT, Wout, woutT);
  gemm_qkv<<<dim3(32, 24), 256, 0, stream>>>(xb, wqkvT, bqkv, Qb, Kb, VTb);
  attn_kernel<<<512, 512, 0, stream>>>(Qb, Kb, VTb, mask, Aatt);
  gemm_out<<<dim3(32, 16), 256, 0, stream>>>(Aatt, woutT, bout, out, 1024);
}